// Round 1
// baseline (105114.795 us; speedup 1.0000x reference)
//
#include <hip/hip_runtime.h>
#include <hip/hip_cooperative_groups.h>
#include <cstddef>
#include <cstdint>

namespace cg = cooperative_groups;

#define T_INN 200
#define T_OUTT 400
#define BB 64
#define DENC 512
#define NMEL 80

typedef unsigned short u16;
typedef __bf16 bf16x8 __attribute__((ext_vector_type(8)));
typedef float f32x4 __attribute__((ext_vector_type(4)));

__device__ __forceinline__ float sigf(float x) { return 1.0f / (1.0f + expf(-x)); }

// round-to-nearest-even f32 -> bf16
__device__ __forceinline__ u16 f2bf(float f) {
  unsigned u = __float_as_uint(f);
  unsigned r = u + 0x7fffu + ((u >> 16) & 1u);
  return (u16)(r >> 16);
}

__device__ __forceinline__ bf16x8 ldbf8(const u16* p) { return *(const bf16x8*)p; }

// ---------------------------------------------------------------------------
// fp32 tiled GEMM for precompute: C[m][n] = act(sum_k A[m][k]*W[n][k])
// grid.x = N/64, grid.y = M/64, block 256. Optional bf16 output.
// ---------------------------------------------------------------------------
__global__ __launch_bounds__(256) void gemm_pre_kernel(
    const float* __restrict__ A, int lda, const float* __restrict__ W, int ldw,
    float* __restrict__ C, u16* __restrict__ Cbf, int ldc, int K, int relu)
{
  __shared__ float As[16][66];
  __shared__ float Ws[16][66];
  const int tid = threadIdx.x;
  const int tn = tid & 15, tm = tid >> 4;
  const int n0 = blockIdx.x * 64;
  const int m0 = blockIdx.y * 64;
  float acc[4][4] = {{0.f}};
  for (int kt = 0; kt < K; kt += 16) {
#pragma unroll
    for (int i = 0; i < 4; i++) {
      int e = tid + 256 * i;
      int m = e >> 4, kk = e & 15;
      As[kk][m] = A[(size_t)(m0 + m) * lda + kt + kk];
    }
#pragma unroll
    for (int i = 0; i < 4; i++) {
      int e = tid + 256 * i;
      int n = e >> 4, kk = e & 15;
      Ws[kk][n] = W[(size_t)(n0 + n) * ldw + kt + kk];
    }
    __syncthreads();
#pragma unroll
    for (int kk = 0; kk < 16; kk++) {
      float2 a01 = *(const float2*)&As[kk][tm * 4];
      float2 a23 = *(const float2*)&As[kk][tm * 4 + 2];
      float2 w01 = *(const float2*)&Ws[kk][tn * 4];
      float2 w23 = *(const float2*)&Ws[kk][tn * 4 + 2];
      float a[4] = {a01.x, a01.y, a23.x, a23.y};
      float w[4] = {w01.x, w01.y, w23.x, w23.y};
#pragma unroll
      for (int mi = 0; mi < 4; mi++)
#pragma unroll
        for (int ni = 0; ni < 4; ni++)
          acc[mi][ni] = fmaf(a[mi], w[ni], acc[mi][ni]);
    }
    __syncthreads();
  }
#pragma unroll
  for (int mi = 0; mi < 4; mi++) {
    int m = m0 + tm * 4 + mi;
    float v0 = acc[mi][0], v1 = acc[mi][1], v2 = acc[mi][2], v3 = acc[mi][3];
    if (relu) {
      v0 = fmaxf(v0, 0.f); v1 = fmaxf(v1, 0.f);
      v2 = fmaxf(v2, 0.f); v3 = fmaxf(v3, 0.f);
    }
    if (Cbf) {
      u16* p = Cbf + (size_t)m * ldc + n0 + tn * 4;
      p[0] = f2bf(v0); p[1] = f2bf(v1); p[2] = f2bf(v2); p[3] = f2bf(v3);
    } else {
      float4 vv; vv.x = v0; vv.y = v1; vv.z = v2; vv.w = v3;
      *(float4*)&C[(size_t)m * ldc + n0 + tn * 4] = vv;
    }
  }
}

// ---------------------------------------------------------------------------
// Weight repack: W[n][k] fp32 -> bf16, MFMA B-fragment lane order.
// slot = (nt*KTtot + kt)*64 + lane ; element j: W[nt*16+(lane&15)][kt*32+(lane>>4)*8+j]
// ---------------------------------------------------------------------------
__global__ __launch_bounds__(256) void pack_w_kernel(
    const float* __restrict__ W, u16* __restrict__ P,
    int K, int KTl, int ktOff, int KTtot, int total)
{
  int slot = blockIdx.x * 256 + threadIdx.x;
  if (slot >= total) return;
  int lane = slot & 63;
  int ktl = (slot >> 6) % KTl;
  int nt = slot / (64 * KTl);
  int n = nt * 16 + (lane & 15);
  int k = ktl * 32 + (lane >> 4) * 8;
  const float* src = W + (size_t)n * K + k;
  u16 tmp[8];
#pragma unroll
  for (int i = 0; i < 8; i++) tmp[i] = f2bf(src[i]);
  u16* dst = P + ((size_t)(nt * KTtot + (ktl + ktOff)) * 64 + lane) * 8;
  *(uint4*)dst = *(const uint4*)tmp;
}

// pm (b*t, a) -> pmT (b, a, t)
__global__ void transpose_pm_kernel(const float* __restrict__ pm, float* __restrict__ pmT)
{
  int b = blockIdx.z;
  int tT = blockIdx.x * 32, aT = blockIdx.y * 32;
  __shared__ float tile[32][33];
  int tx = threadIdx.x, ty = threadIdx.y;
#pragma unroll
  for (int i = 0; i < 4; i++) {
    int t = tT + ty + i * 8;
    int a = aT + tx;
    if (t < T_INN) tile[ty + i * 8][tx] = pm[((size_t)b * T_INN + t) * 128 + a];
  }
  __syncthreads();
#pragma unroll
  for (int i = 0; i < 4; i++) {
    int a = aT + ty + i * 8;
    int t = tT + tx;
    if (t < T_INN) pmT[((size_t)b * 128 + a) * T_INN + t] = tile[tx][ty + i * 8];
  }
}

// ---------------------------------------------------------------------------
// Persistent cooperative decode kernel.
// grid = 64 blocks x 1024 threads. Block b owns:
//   - gate column-quad b (cols b*16..b*16+15 of each of the 4 gates), waves 0-3
//   - attention for batch b (all 1024 threads)
//   - a slice of outproj on waves 4-15 (overlapped with gatesA of next step)
// 3 grid syncs per decode step.
// ---------------------------------------------------------------------------
struct DecParams {
  const u16* xs_bf;        // [400][64][256]
  const u16* Wa;           // packed, KT=56
  const u16* Wd;           // packed, KT=80
  const float* b_a;
  const float* b_d;
  float* ah; float* ac; float* dh; float* dc;
  u16* ah_bf;              // [2][64][1024] parity double-buffered
  u16* dh_bf;              // [2][64][1024]
  float* actx; u16* actx_bf;
  float* aw; float* awcum;
  const float* pmT;
  const float* Wq; const float* Wconv; const float* Wloc; const float* vvec;
  const int* lens; const float* enc;
  const float* Wp; const float* bp;
  float* outsOut; float* alignsOut;
};

// One wave: 1 m-tile (16 batch rows) x 4 gate n-tiles, full K. Then LSTM
// activation in-register and h/c/h_bf stores. bq = column-quad (== blockIdx.x).
template <int KT>
__device__ __forceinline__ void gates_lstm(
    const u16* __restrict__ A0, int k0, int lda0,
    const u16* __restrict__ A1, int k1, int lda1,
    const u16* __restrict__ A2, int lda2,
    const u16* __restrict__ Wpack, const float* __restrict__ bias,
    float* __restrict__ hOut, float* __restrict__ cSt, u16* __restrict__ hbfOut,
    int bq, int w, int lane)
{
  const int mrow = lane & 15;
  const int ksub = (lane >> 4) * 8;
  const int rb = (lane >> 4) * 4;
  const int b01 = k0, b12 = k0 + k1;
  f32x4 acc0 = {0.f, 0.f, 0.f, 0.f};
  f32x4 acc1 = acc0, acc2 = acc0, acc3 = acc0;
  for (int kt = 0; kt < KT; kt++) {
    int kb = kt * 32;
    const u16* Ap; int lda;
    if (kb < b01)      { Ap = A0; lda = lda0; }
    else if (kb < b12) { Ap = A1; lda = lda1; kb -= b01; }
    else               { Ap = A2; lda = lda2; kb -= b12; }
    bf16x8 a = ldbf8(Ap + (size_t)(w * 16 + mrow) * lda + kb + ksub);
    bf16x8 b0 = ldbf8(Wpack + ((size_t)((0 * 64 + bq) * KT + kt) * 64 + lane) * 8);
    bf16x8 b1 = ldbf8(Wpack + ((size_t)((1 * 64 + bq) * KT + kt) * 64 + lane) * 8);
    bf16x8 b2 = ldbf8(Wpack + ((size_t)((2 * 64 + bq) * KT + kt) * 64 + lane) * 8);
    bf16x8 b3 = ldbf8(Wpack + ((size_t)((3 * 64 + bq) * KT + kt) * 64 + lane) * 8);
    acc0 = __builtin_amdgcn_mfma_f32_16x16x32_bf16(a, b0, acc0, 0, 0, 0);
    acc1 = __builtin_amdgcn_mfma_f32_16x16x32_bf16(a, b1, acc1, 0, 0, 0);
    acc2 = __builtin_amdgcn_mfma_f32_16x16x32_bf16(a, b2, acc2, 0, 0, 0);
    acc3 = __builtin_amdgcn_mfma_f32_16x16x32_bf16(a, b3, acc3, 0, 0, 0);
  }
  const int j = bq * 16 + mrow;
#pragma unroll
  for (int r = 0; r < 4; r++) {
    int m = w * 16 + rb + r;
    size_t idx = (size_t)m * 1024 + j;
    float gi = acc0[r] + bias[j];
    float gf = acc1[r] + bias[j + 1024];
    float gg = acc2[r] + bias[j + 2048];
    float go = acc3[r] + bias[j + 3072];
    float cn = sigf(gf) * cSt[idx] + sigf(gi) * tanhf(gg);
    cSt[idx] = cn;
    float hn = sigf(go) * tanhf(cn);
    hOut[idx] = hn;
    hbfOut[idx] = f2bf(hn);
  }
}

__global__ __launch_bounds__(1024) void decode_kernel(DecParams p)
{
  cg::grid_group grid = cg::this_grid();
  const int b = blockIdx.x;          // 0..63: batch AND column-quad
  const int tid = threadIdx.x;
  const int w = tid >> 6, lane = tid & 63;
  const int g = tid >> 8, ti = tid & 255;

  __shared__ float aS[T_INN], cS[T_INN], ahS[1024];
  __shared__ float pp[128][9];
  __shared__ float pqS[128];
  __shared__ float convS[T_INN][33];
  __shared__ float ep[4][256];
  __shared__ float red[256];
  __shared__ float awS[256];
  __shared__ float cpart[1024];

  for (int t = 0; t <= T_OUTT; t++) {
    u16* ahw = p.ah_bf + (size_t)(t & 1) * 65536;
    const u16* ahr = p.ah_bf + (size_t)((t + 1) & 1) * 65536;
    u16* dhw = p.dh_bf + (size_t)(t & 1) * 65536;
    const u16* dhr = p.dh_bf + (size_t)((t + 1) & 1) * 65536;

    // ---- phase 1: gatesA+lstmA (waves 0-3)  ||  outproj(t-1) (waves 4-15)
    if (w < 4) {
      if (t < T_OUTT)
        gates_lstm<56>(p.xs_bf + (size_t)t * 64 * 256, 256, 256,
                       p.actx_bf, 512, 512,
                       ahr, 1024,
                       p.Wa, p.b_a, p.ah, p.ac, ahw, b, w, lane);
    } else if (t >= 1) {
      const int tt = t - 1;
      int wl = (b * 12 + (w - 4)) * 64 + lane;
      int o = wl >> 3, sub = wl & 7;
      if (o < 5120) {
        int bo = o / 80, m = o - bo * 80;
        const float* wrow = p.Wp + (size_t)m * 1536 + sub * 192;
        float s = 0.f;
#pragma unroll
        for (int kk = 0; kk < 48; kk++) {
          int k = sub * 192 + kk * 4;
          float4 wv = *(const float4*)(wrow + kk * 4);
          float4 av = (k < 1024)
              ? *(const float4*)(p.dh + (size_t)bo * 1024 + k)
              : *(const float4*)(p.actx + (size_t)bo * 512 + (k - 1024));
          s += wv.x * av.x + wv.y * av.y + wv.z * av.z + wv.w * av.w;
        }
        s += __shfl_xor(s, 1);
        s += __shfl_xor(s, 2);
        s += __shfl_xor(s, 4);
        if (sub == 0)
          p.outsOut[((size_t)bo * T_OUTT + tt) * NMEL + m] = s + p.bp[m];
      }
    }
    grid.sync();
    if (t == T_OUTT) break;

    // ---- phase 2: attention for batch b (all 1024 threads)
    if (tid < T_INN) { aS[tid] = p.aw[b * T_INN + tid]; cS[tid] = p.awcum[b * T_INN + tid]; }
    ahS[tid] = p.ah[(size_t)b * 1024 + tid];
    __syncthreads();
    {
      int a = tid >> 3, kc = tid & 7;
      const float4* wv = (const float4*)(p.Wq + (size_t)a * 1024 + kc * 128);
      const float4* hv = (const float4*)(ahS + kc * 128);
      float s = 0.f;
#pragma unroll 8
      for (int i = 0; i < 32; i++) {
        float4 wq = wv[i], hh = hv[i];
        s += wq.x * hh.x + wq.y * hh.y + wq.z * hh.z + wq.w * hh.w;
      }
      pp[a][kc] = s;
    }
    __syncthreads();
    if (tid < 128) {
      float s = 0.f;
#pragma unroll
      for (int kc = 0; kc < 8; kc++) s += pp[tid][kc];
      pqS[tid] = s;
    }
    if (ti < T_INN) {
#pragma unroll
      for (int f8 = 0; f8 < 8; f8++) {
        int f = g * 8 + f8;
        float s = 0.f;
#pragma unroll
        for (int k = 0; k < 31; k++) {
          int tt2 = ti + k - 15;
          if (tt2 >= 0 && tt2 < T_INN)
            s += p.Wconv[f * 62 + k] * aS[tt2] + p.Wconv[f * 62 + 31 + k] * cS[tt2];
        }
        convS[ti][f] = s;
      }
    }
    __syncthreads();
    float e = 0.f;
    if (ti < T_INN) {
      const float* pm = p.pmT + ((size_t)b * 128 + g * 32) * T_INN + ti;
#pragma unroll 4
      for (int aa = 0; aa < 32; aa++) {
        int a = g * 32 + aa;
        float x = pqS[a] + pm[(size_t)aa * T_INN];
        const float* wl2 = p.Wloc + a * 32;
#pragma unroll
        for (int f = 0; f < 32; f++) x += wl2[f] * convS[ti][f];
        e += p.vvec[a] * tanhf(x);
      }
    }
    ep[g][ti] = e;
    __syncthreads();
    float ev = -3.0e38f, ex = 0.f;
    if (tid < 256) {
      if (tid < T_INN) {
        ev = ep[0][tid] + ep[1][tid] + ep[2][tid] + ep[3][tid];
        if (tid >= p.lens[b]) ev = -100000000.0f;
      }
      red[tid] = ev;
    }
    __syncthreads();
    for (int s2 = 128; s2 > 0; s2 >>= 1) {
      if (tid < s2) red[tid] = fmaxf(red[tid], red[tid + s2]);
      __syncthreads();
    }
    float mx = red[0];
    __syncthreads();
    if (tid < 256) { ex = (tid < T_INN) ? expf(ev - mx) : 0.f; red[tid] = ex; }
    __syncthreads();
    for (int s2 = 128; s2 > 0; s2 >>= 1) {
      if (tid < s2) red[tid] += red[tid + s2];
      __syncthreads();
    }
    float inv = 1.0f / red[0];
    if (tid < T_INN) {
      float a = ex * inv;
      awS[tid] = a;
      p.aw[b * T_INN + tid] = a;
      p.awcum[b * T_INN + tid] = cS[tid] + a;
      p.alignsOut[((size_t)b * T_OUTT + t) * T_INN + tid] = a;
    }
    __syncthreads();
    {
      int e0 = tid & 511, half = tid >> 9;
      const float* ep2 = p.enc + ((size_t)b * T_INN + half * 100) * DENC + e0;
      float s = 0.f;
#pragma unroll 4
      for (int tt2 = 0; tt2 < 100; tt2++) s += awS[half * 100 + tt2] * ep2[(size_t)tt2 * DENC];
      cpart[tid] = s;
    }
    __syncthreads();
    if (tid < 512) {
      float v2 = cpart[tid] + cpart[512 + tid];
      p.actx[b * DENC + tid] = v2;
      p.actx_bf[b * DENC + tid] = f2bf(v2);
    }
    grid.sync();

    // ---- phase 3: gatesD + lstmD (waves 0-3)
    if (w < 4)
      gates_lstm<80>(ahw, 1024, 1024,
                     p.actx_bf, 512, 512,
                     dhr, 1024,
                     p.Wd, p.b_d, p.dh, p.dc, dhw, b, w, lane);
    grid.sync();
  }
}

extern "C" void kernel_launch(void* const* d_in, const int* in_sizes, int n_in,
                              void* d_out, int out_size, void* d_ws, size_t ws_size,
                              hipStream_t stream)
{
  const float* enc    = (const float*)d_in[0];
  const float* dec    = (const float*)d_in[1];
  const int*   lens   = (const int*)d_in[2];
  const float* W_p1   = (const float*)d_in[3];
  const float* W_p2   = (const float*)d_in[4];
  const float* W_ih_a = (const float*)d_in[5];
  const float* W_hh_a = (const float*)d_in[6];
  const float* b_a    = (const float*)d_in[7];
  const float* Wq     = (const float*)d_in[8];
  const float* Wmem   = (const float*)d_in[9];
  const float* vvec   = (const float*)d_in[10];
  const float* Wconv  = (const float*)d_in[11];
  const float* Wloc   = (const float*)d_in[12];
  const float* W_ih_d = (const float*)d_in[13];
  const float* W_hh_d = (const float*)d_in[14];
  const float* b_d    = (const float*)d_in[15];
  const float* Wp     = (const float*)d_in[16];
  const float* bp     = (const float*)d_in[17];

  float* ws = (float*)d_ws;
  size_t off = 0;
  u16* xs_bf = (u16*)(ws + off); off += (size_t)T_OUTT * 64 * 256 / 2;   // 3.28M fl
  float* pmT = ws + off; off += (size_t)64 * 128 * T_INN;                 // 1.64M fl
  u16* Wa_pack = (u16*)(ws + off); off += (size_t)4096 * 1792 / 2;        // 3.67M fl
  u16* Wd_pack = (u16*)(ws + off); off += (size_t)4096 * 2560 / 2;        // 5.24M fl
  // state block (zero-initialized)
  float* stateBase = ws + off;
  float* ah    = stateBase;
  float* ac    = ah + 65536;
  float* dh    = ac + 65536;
  float* dc    = dh + 65536;
  float* actx  = dc + 65536;          // 64*512
  float* aw    = actx + 32768;        // 64*200
  float* awcum = aw + 12800;
  u16* ah_bf   = (u16*)(awcum + 12800);          // 2 x 65536 u16 (parity dbuf)
  u16* dh_bf   = ah_bf + 2 * 65536;              // 2 x 65536 u16
  u16* actx_bf = dh_bf + 2 * 65536;              // 32768 u16
  size_t stateFloats = 4 * 65536 + 32768 + 2 * 12800
                     + (2 * 65536 + 2 * 65536 + 32768) / 2;
  off += stateFloats;
  float* scratch = ws + off;          // h1 (prenet) / pmt (pm) — precompute only
  float* h1 = scratch;                               // 399*64 x 256
  float* pmt = scratch;                              // reused after prenet

  float* outsOut   = (float*)d_out;
  float* alignsOut = outsOut + (size_t)BB * T_OUTT * NMEL;

  // zero recurrent state + t=0 prenet row (prenet(0)=0, no bias)
  hipMemsetAsync(stateBase, 0, stateFloats * sizeof(float), stream);
  hipMemsetAsync(xs_bf, 0, (size_t)64 * 256 * sizeof(u16), stream);

  // ---- precompute ----
  {
    int tot;
    tot = 256 * 24 * 64;
    pack_w_kernel<<<(tot + 255) / 256, 256, 0, stream>>>(W_ih_a, Wa_pack, 768, 24, 0, 56, tot);
    tot = 256 * 32 * 64;
    pack_w_kernel<<<(tot + 255) / 256, 256, 0, stream>>>(W_hh_a, Wa_pack, 1024, 32, 24, 56, tot);
    tot = 256 * 48 * 64;
    pack_w_kernel<<<(tot + 255) / 256, 256, 0, stream>>>(W_ih_d, Wd_pack, 1536, 48, 0, 80, tot);
    tot = 256 * 32 * 64;
    pack_w_kernel<<<(tot + 255) / 256, 256, 0, stream>>>(W_hh_d, Wd_pack, 1024, 32, 48, 80, tot);
  }
  gemm_pre_kernel<<<dim3(4, 399), 256, 0, stream>>>(dec, 80, W_p1, 80, h1, nullptr, 256, 80, 1);
  gemm_pre_kernel<<<dim3(4, 399), 256, 0, stream>>>(h1, 256, W_p2, 256, nullptr, xs_bf + 64 * 256, 256, 256, 1);
  gemm_pre_kernel<<<dim3(2, 200), 256, 0, stream>>>(enc, 512, Wmem, 512, pmt, nullptr, 128, 512, 0);
  transpose_pm_kernel<<<dim3(7, 4, 64), dim3(32, 8), 0, stream>>>(pmt, pmT);

  // ---- persistent cooperative decode loop ----
  DecParams dp;
  dp.xs_bf = xs_bf; dp.Wa = Wa_pack; dp.Wd = Wd_pack;
  dp.b_a = b_a; dp.b_d = b_d;
  dp.ah = ah; dp.ac = ac; dp.dh = dh; dp.dc = dc;
  dp.ah_bf = ah_bf; dp.dh_bf = dh_bf;
  dp.actx = actx; dp.actx_bf = actx_bf;
  dp.aw = aw; dp.awcum = awcum;
  dp.pmT = pmT; dp.Wq = Wq; dp.Wconv = Wconv; dp.Wloc = Wloc; dp.vvec = vvec;
  dp.lens = lens; dp.enc = enc; dp.Wp = Wp; dp.bp = bp;
  dp.outsOut = outsOut; dp.alignsOut = alignsOut;

  void* kargs[] = { (void*)&dp };
  hipLaunchCooperativeKernel(decode_kernel, dim3(64), dim3(1024), kargs, 0, stream);
}

// Round 2
// 74819.556 us; speedup vs baseline: 1.4049x; 1.4049x over previous
//
#include <hip/hip_runtime.h>
#include <hip/hip_cooperative_groups.h>
#include <cstddef>
#include <cstdint>

namespace cg = cooperative_groups;

#define T_INN 200
#define T_OUTT 400
#define BB 64
#define DENC 512
#define NMEL 80

typedef unsigned short u16;
typedef __bf16 bf16x8 __attribute__((ext_vector_type(8)));
typedef float f32x4 __attribute__((ext_vector_type(4)));

__device__ __forceinline__ float sigf(float x) { return 1.0f / (1.0f + expf(-x)); }

// round-to-nearest-even f32 -> bf16
__device__ __forceinline__ u16 f2bf(float f) {
  unsigned u = __float_as_uint(f);
  unsigned r = u + 0x7fffu + ((u >> 16) & 1u);
  return (u16)(r >> 16);
}

__device__ __forceinline__ bf16x8 ldbf8(const u16* p) { return *(const bf16x8*)p; }

// ---------------------------------------------------------------------------
// fp32 tiled GEMM for precompute: C[m][n] = act(sum_k A[m][k]*W[n][k])
// ---------------------------------------------------------------------------
__global__ __launch_bounds__(256) void gemm_pre_kernel(
    const float* __restrict__ A, int lda, const float* __restrict__ W, int ldw,
    float* __restrict__ C, u16* __restrict__ Cbf, int ldc, int K, int relu)
{
  __shared__ float As[16][66];
  __shared__ float Ws[16][66];
  const int tid = threadIdx.x;
  const int tn = tid & 15, tm = tid >> 4;
  const int n0 = blockIdx.x * 64;
  const int m0 = blockIdx.y * 64;
  float acc[4][4] = {{0.f}};
  for (int kt = 0; kt < K; kt += 16) {
#pragma unroll
    for (int i = 0; i < 4; i++) {
      int e = tid + 256 * i;
      int m = e >> 4, kk = e & 15;
      As[kk][m] = A[(size_t)(m0 + m) * lda + kt + kk];
    }
#pragma unroll
    for (int i = 0; i < 4; i++) {
      int e = tid + 256 * i;
      int n = e >> 4, kk = e & 15;
      Ws[kk][n] = W[(size_t)(n0 + n) * ldw + kt + kk];
    }
    __syncthreads();
#pragma unroll
    for (int kk = 0; kk < 16; kk++) {
      float2 a01 = *(const float2*)&As[kk][tm * 4];
      float2 a23 = *(const float2*)&As[kk][tm * 4 + 2];
      float2 w01 = *(const float2*)&Ws[kk][tn * 4];
      float2 w23 = *(const float2*)&Ws[kk][tn * 4 + 2];
      float a[4] = {a01.x, a01.y, a23.x, a23.y};
      float w[4] = {w01.x, w01.y, w23.x, w23.y};
#pragma unroll
      for (int mi = 0; mi < 4; mi++)
#pragma unroll
        for (int ni = 0; ni < 4; ni++)
          acc[mi][ni] = fmaf(a[mi], w[ni], acc[mi][ni]);
    }
    __syncthreads();
  }
#pragma unroll
  for (int mi = 0; mi < 4; mi++) {
    int m = m0 + tm * 4 + mi;
    float v0 = acc[mi][0], v1 = acc[mi][1], v2 = acc[mi][2], v3 = acc[mi][3];
    if (relu) {
      v0 = fmaxf(v0, 0.f); v1 = fmaxf(v1, 0.f);
      v2 = fmaxf(v2, 0.f); v3 = fmaxf(v3, 0.f);
    }
    if (Cbf) {
      u16* p = Cbf + (size_t)m * ldc + n0 + tn * 4;
      p[0] = f2bf(v0); p[1] = f2bf(v1); p[2] = f2bf(v2); p[3] = f2bf(v3);
    } else {
      float4 vv; vv.x = v0; vv.y = v1; vv.z = v2; vv.w = v3;
      *(float4*)&C[(size_t)m * ldc + n0 + tn * 4] = vv;
    }
  }
}

// ---------------------------------------------------------------------------
// Weight repack: W[n][k] fp32 -> bf16, MFMA B-fragment lane order.
// ---------------------------------------------------------------------------
__global__ __launch_bounds__(256) void pack_w_kernel(
    const float* __restrict__ W, u16* __restrict__ P,
    int K, int KTl, int ktOff, int KTtot, int total)
{
  int slot = blockIdx.x * 256 + threadIdx.x;
  if (slot >= total) return;
  int lane = slot & 63;
  int ktl = (slot >> 6) % KTl;
  int nt = slot / (64 * KTl);
  int n = nt * 16 + (lane & 15);
  int k = ktl * 32 + (lane >> 4) * 8;
  const float* src = W + (size_t)n * K + k;
  u16 tmp[8];
#pragma unroll
  for (int i = 0; i < 8; i++) tmp[i] = f2bf(src[i]);
  u16* dst = P + ((size_t)(nt * KTtot + (ktl + ktOff)) * 64 + lane) * 8;
  *(uint4*)dst = *(const uint4*)tmp;
}

// pm (b*t, a) -> pmT (b, a, t)
__global__ void transpose_pm_kernel(const float* __restrict__ pm, float* __restrict__ pmT)
{
  int b = blockIdx.z;
  int tT = blockIdx.x * 32, aT = blockIdx.y * 32;
  __shared__ float tile[32][33];
  int tx = threadIdx.x, ty = threadIdx.y;
#pragma unroll
  for (int i = 0; i < 4; i++) {
    int t = tT + ty + i * 8;
    int a = aT + tx;
    if (t < T_INN) tile[ty + i * 8][tx] = pm[((size_t)b * T_INN + t) * 128 + a];
  }
  __syncthreads();
#pragma unroll
  for (int i = 0; i < 4; i++) {
    int a = aT + ty + i * 8;
    int t = tT + tx;
    if (t < T_INN) pmT[((size_t)b * 128 + a) * T_INN + t] = tile[tx][ty + i * 8];
  }
}

// ---------------------------------------------------------------------------
// Persistent cooperative decode kernel, 256 blocks x 1024 threads.
// Block b: gate tile (quad bq = b&63 -> cols bq*16..+15 of each gate,
//          m-slice ms = b>>6 -> batches ms*16..+15), K split over 16 waves.
// Phase B: attention (blocks 0-63, batch=b) || outproj(t-1) (blocks 64-127).
// 2 grid syncs per step.
// ---------------------------------------------------------------------------
struct SmemGates {
  float part[16][64][16];   // [wave][lane][gate*4+reg] fp32 partials (64 KB)
  float gred[1024];
};
struct SmemAtt {
  float aS[T_INN], cS[T_INN], ahS[1024];
  float pp[128][9];
  float pqS[128];
  float convS[T_INN][33];
  float ep[4][256];
  float red[256];
  float awS[256];
  float cpart[1024];
};
union Smem { SmemGates g; SmemAtt a; };

struct DecParams {
  const u16* xs_bf;        // [400][64][256]
  const u16* Wa;           // packed, KT=56
  const u16* Wd;           // packed, KT=80
  const float* b_a;
  const float* b_d;
  float* ah; float* ac; float* dh; float* dc;
  u16* ah_bf;              // [2][64][1024] parity buffers
  u16* dh_bf;              // [2][64][1024]
  float* actx;             // [2][64][512] parity
  u16* actx_bf;            // [2][64][512] parity
  float* aw; float* awcum;
  const float* pmT;
  const float* Wq; const float* Wconv; const float* Wloc; const float* vvec;
  const int* lens; const float* enc;
  const float* Wp; const float* bp;
  float* outsOut; float* alignsOut;
};

// Full-block gates GEMM + LSTM activation. 16-wave split-K, LDS reduce.
template <int KT>
__device__ __forceinline__ void gates_lstm_block(
    const u16* __restrict__ A0, int k0, int lda0,
    const u16* __restrict__ A1, int k1, int lda1,
    const u16* __restrict__ A2, int lda2,
    const u16* __restrict__ Wpack, const float* __restrict__ bias,
    float* __restrict__ hOut, float* __restrict__ cSt, u16* __restrict__ hbfOut,
    int bq, int ms, int tid, SmemGates& sg)
{
  const int kw = tid >> 6, lane = tid & 63;
  const int mrow = lane & 15, ksub = (lane >> 4) * 8;
  const int b01 = k0, b12 = k0 + k1;
  const size_t gstride = (size_t)KT * 32768;   // u16 elems between gate blocks
  f32x4 acc0 = {0.f, 0.f, 0.f, 0.f};
  f32x4 acc1 = acc0, acc2 = acc0, acc3 = acc0;
  for (int kt = kw; kt < KT; kt += 16) {
    int kb = kt * 32;
    const u16* Ap; int lda;
    if (kb < b01)      { Ap = A0; lda = lda0; }
    else if (kb < b12) { Ap = A1; lda = lda1; kb -= b01; }
    else               { Ap = A2; lda = lda2; kb -= b12; }
    bf16x8 a = ldbf8(Ap + (size_t)(ms * 16 + mrow) * lda + kb + ksub);
    const u16* wb = Wpack + ((size_t)(bq * KT + kt) * 64 + lane) * 8;
    bf16x8 bv0 = ldbf8(wb);
    bf16x8 bv1 = ldbf8(wb + gstride);
    bf16x8 bv2 = ldbf8(wb + 2 * gstride);
    bf16x8 bv3 = ldbf8(wb + 3 * gstride);
    acc0 = __builtin_amdgcn_mfma_f32_16x16x32_bf16(a, bv0, acc0, 0, 0, 0);
    acc1 = __builtin_amdgcn_mfma_f32_16x16x32_bf16(a, bv1, acc1, 0, 0, 0);
    acc2 = __builtin_amdgcn_mfma_f32_16x16x32_bf16(a, bv2, acc2, 0, 0, 0);
    acc3 = __builtin_amdgcn_mfma_f32_16x16x32_bf16(a, bv3, acc3, 0, 0, 0);
  }
  *(f32x4*)&sg.part[kw][lane][0]  = acc0;
  *(f32x4*)&sg.part[kw][lane][4]  = acc1;
  *(f32x4*)&sg.part[kw][lane][8]  = acc2;
  *(f32x4*)&sg.part[kw][lane][12] = acc3;
  __syncthreads();
  {
    int g = tid >> 8, rc = tid & 255, row = rc >> 4, col = rc & 15;
    int ln = ((row >> 2) << 4) + col;
    int idx4 = g * 4 + (row & 3);
    float s = 0.f;
#pragma unroll
    for (int k2 = 0; k2 < 16; k2++) s += sg.part[k2][ln][idx4];
    sg.gred[tid] = s;
  }
  __syncthreads();
  if (tid < 256) {
    int row = tid >> 4, col = tid & 15;
    int j = bq * 16 + col, m = ms * 16 + row;
    size_t idx = (size_t)m * 1024 + j;
    float gi = sg.gred[tid]       + bias[j];
    float gf = sg.gred[256 + tid] + bias[j + 1024];
    float gg = sg.gred[512 + tid] + bias[j + 2048];
    float go = sg.gred[768 + tid] + bias[j + 3072];
    float cn = sigf(gf) * cSt[idx] + sigf(gi) * tanhf(gg);
    cSt[idx] = cn;
    float hn = sigf(go) * tanhf(cn);
    hOut[idx] = hn;
    hbfOut[idx] = f2bf(hn);
  }
}

__global__ __launch_bounds__(1024, 4) void decode_kernel(DecParams p)
{
  cg::grid_group grid = cg::this_grid();
  const int b = blockIdx.x;
  const int bq = b & 63, ms = b >> 6;
  const int tid = threadIdx.x;
  const int g = tid >> 8, ti = tid & 255;

  __shared__ Smem sm;

  for (int t = 0; t <= T_OUTT; t++) {
    // ---------------- phase A: gatesD(t-1) then gatesA(t), all blocks -------
    if (t >= 1) {
      // gatesD(t-1): reads ah_bf[(t-1)&1], actx_bf[(t-1)&1], dh_bf[t&1];
      // writes dh, dc, dh_bf[(t-1)&1]
      gates_lstm_block<80>(
          p.ah_bf + (size_t)((t - 1) & 1) * 65536, 1024, 1024,
          p.actx_bf + (size_t)((t - 1) & 1) * 32768, 512, 512,
          p.dh_bf + (size_t)(t & 1) * 65536, 1024,
          p.Wd, p.b_d, p.dh, p.dc,
          p.dh_bf + (size_t)((t - 1) & 1) * 65536,
          bq, ms, tid, sm.g);
    }
    if (t < T_OUTT) {
      // gatesA(t): reads xs(t), actx_bf[(t+1)&1] (=t-1), ah_bf[(t+1)&1] (=t-1);
      // writes ah, ac, ah_bf[t&1]
      gates_lstm_block<56>(
          p.xs_bf + (size_t)t * 64 * 256, 256, 256,
          p.actx_bf + (size_t)((t + 1) & 1) * 32768, 512, 512,
          p.ah_bf + (size_t)((t + 1) & 1) * 65536, 1024,
          p.Wa, p.b_a, p.ah, p.ac,
          p.ah_bf + (size_t)(t & 1) * 65536,
          bq, ms, tid, sm.g);
    }
    grid.sync();

    // ---------------- phase B: attention(t) || outproj(t-1) -----------------
    if (b < 64) {
      if (t < T_OUTT) {
        SmemAtt& sa = sm.a;
        float* actxW = p.actx + (size_t)(t & 1) * 32768;
        u16* actx_bfW = p.actx_bf + (size_t)(t & 1) * 32768;
        if (tid < T_INN) { sa.aS[tid] = p.aw[b * T_INN + tid]; sa.cS[tid] = p.awcum[b * T_INN + tid]; }
        sa.ahS[tid] = p.ah[(size_t)b * 1024 + tid];
        __syncthreads();
        {
          int a = tid >> 3, kc = tid & 7;
          const float4* wv = (const float4*)(p.Wq + (size_t)a * 1024 + kc * 128);
          const float4* hv = (const float4*)(sa.ahS + kc * 128);
          float s = 0.f;
#pragma unroll 8
          for (int i = 0; i < 32; i++) {
            float4 wq = wv[i], hh = hv[i];
            s += wq.x * hh.x + wq.y * hh.y + wq.z * hh.z + wq.w * hh.w;
          }
          sa.pp[a][kc] = s;
        }
        __syncthreads();
        if (tid < 128) {
          float s = 0.f;
#pragma unroll
          for (int kc = 0; kc < 8; kc++) s += sa.pp[tid][kc];
          sa.pqS[tid] = s;
        }
        if (ti < T_INN) {
#pragma unroll
          for (int f8 = 0; f8 < 8; f8++) {
            int f = g * 8 + f8;
            float s = 0.f;
#pragma unroll
            for (int k = 0; k < 31; k++) {
              int tt2 = ti + k - 15;
              if (tt2 >= 0 && tt2 < T_INN)
                s += p.Wconv[f * 62 + k] * sa.aS[tt2] + p.Wconv[f * 62 + 31 + k] * sa.cS[tt2];
            }
            sa.convS[ti][f] = s;
          }
        }
        __syncthreads();
        float e = 0.f;
        if (ti < T_INN) {
          const float* pm = p.pmT + ((size_t)b * 128 + g * 32) * T_INN + ti;
#pragma unroll 4
          for (int aa = 0; aa < 32; aa++) {
            int a = g * 32 + aa;
            float x = sa.pqS[a] + pm[(size_t)aa * T_INN];
            const float* wl2 = p.Wloc + a * 32;
#pragma unroll
            for (int f = 0; f < 32; f++) x += wl2[f] * sa.convS[ti][f];
            e += p.vvec[a] * tanhf(x);
          }
        }
        sa.ep[g][ti] = e;
        __syncthreads();
        float ev = -3.0e38f, ex = 0.f;
        if (tid < 256) {
          if (tid < T_INN) {
            ev = sa.ep[0][tid] + sa.ep[1][tid] + sa.ep[2][tid] + sa.ep[3][tid];
            if (tid >= p.lens[b]) ev = -100000000.0f;
          }
          sa.red[tid] = ev;
        }
        __syncthreads();
        for (int s2 = 128; s2 > 0; s2 >>= 1) {
          if (tid < s2) sa.red[tid] = fmaxf(sa.red[tid], sa.red[tid + s2]);
          __syncthreads();
        }
        float mx = sa.red[0];
        __syncthreads();
        if (tid < 256) { ex = (tid < T_INN) ? expf(ev - mx) : 0.f; sa.red[tid] = ex; }
        __syncthreads();
        for (int s2 = 128; s2 > 0; s2 >>= 1) {
          if (tid < s2) sa.red[tid] += sa.red[tid + s2];
          __syncthreads();
        }
        float inv = 1.0f / sa.red[0];
        if (tid < T_INN) {
          float a = ex * inv;
          sa.awS[tid] = a;
          p.aw[b * T_INN + tid] = a;
          p.awcum[b * T_INN + tid] = sa.cS[tid] + a;
          p.alignsOut[((size_t)b * T_OUTT + t) * T_INN + tid] = a;
        }
        __syncthreads();
        {
          int e0 = tid & 511, half = tid >> 9;
          const float* ep2 = p.enc + ((size_t)b * T_INN + half * 100) * DENC + e0;
          float s = 0.f;
#pragma unroll 4
          for (int tt2 = 0; tt2 < 100; tt2++) s += sa.awS[half * 100 + tt2] * ep2[(size_t)tt2 * DENC];
          sa.cpart[tid] = s;
        }
        __syncthreads();
        if (tid < 512) {
          float v2 = sa.cpart[tid] + sa.cpart[512 + tid];
          actxW[b * DENC + tid] = v2;
          actx_bfW[b * DENC + tid] = f2bf(v2);
        }
      }
    } else if (b < 128) {
      if (t >= 1) {
        // outproj(t-1) for batch bo: reads dh (epoch t-1), actx[(t-1)&1]
        const int bo = b - 64;
        const float* actxR = p.actx + (size_t)((t - 1) & 1) * 32768;
        float s = 0.f;
        int m = tid / 12, sub = tid - m * 12;
        if (tid < 960) {
          const float4* w4 = (const float4*)(p.Wp + (size_t)m * 1536 + sub * 128);
          const float4* a4 = (sub < 8)
              ? (const float4*)(p.dh + (size_t)bo * 1024 + sub * 128)
              : (const float4*)(actxR + (size_t)bo * 512 + (sub - 8) * 128);
#pragma unroll 8
          for (int kk = 0; kk < 32; kk++) {
            float4 w = w4[kk], av = a4[kk];
            s += w.x * av.x + w.y * av.y + w.z * av.z + w.w * av.w;
          }
        }
        sm.g.gred[tid] = s;
        __syncthreads();
        if (tid < 80) {
          float acc2 = p.bp[tid];
#pragma unroll
          for (int i2 = 0; i2 < 12; i2++) acc2 += sm.g.gred[tid * 12 + i2];
          p.outsOut[((size_t)bo * T_OUTT + (t - 1)) * NMEL + tid] = acc2;
        }
      }
    }
    if (t == T_OUTT) break;
    grid.sync();
  }
}

extern "C" void kernel_launch(void* const* d_in, const int* in_sizes, int n_in,
                              void* d_out, int out_size, void* d_ws, size_t ws_size,
                              hipStream_t stream)
{
  const float* enc    = (const float*)d_in[0];
  const float* dec    = (const float*)d_in[1];
  const int*   lens   = (const int*)d_in[2];
  const float* W_p1   = (const float*)d_in[3];
  const float* W_p2   = (const float*)d_in[4];
  const float* W_ih_a = (const float*)d_in[5];
  const float* W_hh_a = (const float*)d_in[6];
  const float* b_a    = (const float*)d_in[7];
  const float* Wq     = (const float*)d_in[8];
  const float* Wmem   = (const float*)d_in[9];
  const float* vvec   = (const float*)d_in[10];
  const float* Wconv  = (const float*)d_in[11];
  const float* Wloc   = (const float*)d_in[12];
  const float* W_ih_d = (const float*)d_in[13];
  const float* W_hh_d = (const float*)d_in[14];
  const float* b_d    = (const float*)d_in[15];
  const float* Wp     = (const float*)d_in[16];
  const float* bp     = (const float*)d_in[17];

  float* ws = (float*)d_ws;
  size_t off = 0;
  u16* xs_bf = (u16*)(ws + off); off += (size_t)T_OUTT * 64 * 256 / 2;
  float* pmT = ws + off; off += (size_t)64 * 128 * T_INN;
  u16* Wa_pack = (u16*)(ws + off); off += (size_t)4096 * 1792 / 2;
  u16* Wd_pack = (u16*)(ws + off); off += (size_t)4096 * 2560 / 2;
  // state block (zero-initialized)
  float* stateBase = ws + off;
  float* ah    = stateBase;
  float* ac    = ah + 65536;
  float* dh    = ac + 65536;
  float* dc    = dh + 65536;
  float* actx  = dc + 65536;          // 2 x 64*512 (parity)
  float* aw    = actx + 2 * 32768;    // 64*200
  float* awcum = aw + 12800;
  u16* ah_bf   = (u16*)(awcum + 12800);          // 2 x 65536 u16
  u16* dh_bf   = ah_bf + 2 * 65536;              // 2 x 65536 u16
  u16* actx_bf = dh_bf + 2 * 65536;              // 2 x 32768 u16
  size_t stateFloats = 4 * 65536 + 2 * 32768 + 2 * 12800
                     + (2 * 65536 + 2 * 65536 + 2 * 32768) / 2;
  off += stateFloats;
  float* scratch = ws + off;          // precompute only
  float* h1 = scratch;                // 399*64 x 256
  float* pmt = scratch;               // reused after prenet

  float* outsOut   = (float*)d_out;
  float* alignsOut = outsOut + (size_t)BB * T_OUTT * NMEL;

  // zero recurrent state + t=0 prenet row (prenet(0)=0, no bias)
  hipMemsetAsync(stateBase, 0, stateFloats * sizeof(float), stream);
  hipMemsetAsync(xs_bf, 0, (size_t)64 * 256 * sizeof(u16), stream);

  // ---- precompute ----
  {
    int tot;
    tot = 256 * 24 * 64;
    pack_w_kernel<<<(tot + 255) / 256, 256, 0, stream>>>(W_ih_a, Wa_pack, 768, 24, 0, 56, tot);
    tot = 256 * 32 * 64;
    pack_w_kernel<<<(tot + 255) / 256, 256, 0, stream>>>(W_hh_a, Wa_pack, 1024, 32, 24, 56, tot);
    tot = 256 * 48 * 64;
    pack_w_kernel<<<(tot + 255) / 256, 256, 0, stream>>>(W_ih_d, Wd_pack, 1536, 48, 0, 80, tot);
    tot = 256 * 32 * 64;
    pack_w_kernel<<<(tot + 255) / 256, 256, 0, stream>>>(W_hh_d, Wd_pack, 1024, 32, 48, 80, tot);
  }
  gemm_pre_kernel<<<dim3(4, 399), 256, 0, stream>>>(dec, 80, W_p1, 80, h1, nullptr, 256, 80, 1);
  gemm_pre_kernel<<<dim3(4, 399), 256, 0, stream>>>(h1, 256, W_p2, 256, nullptr, xs_bf + 64 * 256, 256, 256, 1);
  gemm_pre_kernel<<<dim3(2, 200), 256, 0, stream>>>(enc, 512, Wmem, 512, pmt, nullptr, 128, 512, 0);
  transpose_pm_kernel<<<dim3(7, 4, 64), dim3(32, 8), 0, stream>>>(pmt, pmT);

  // ---- persistent cooperative decode loop ----
  DecParams dp;
  dp.xs_bf = xs_bf; dp.Wa = Wa_pack; dp.Wd = Wd_pack;
  dp.b_a = b_a; dp.b_d = b_d;
  dp.ah = ah; dp.ac = ac; dp.dh = dh; dp.dc = dc;
  dp.ah_bf = ah_bf; dp.dh_bf = dh_bf;
  dp.actx = actx; dp.actx_bf = actx_bf;
  dp.aw = aw; dp.awcum = awcum;
  dp.pmT = pmT; dp.Wq = Wq; dp.Wconv = Wconv; dp.Wloc = Wloc; dp.vvec = vvec;
  dp.lens = lens; dp.enc = enc; dp.Wp = Wp; dp.bp = bp;
  dp.outsOut = outsOut; dp.alignsOut = alignsOut;

  void* kargs[] = { (void*)&dp };
  hipLaunchCooperativeKernel(decode_kernel, dim3(256), dim3(1024), kargs, 0, stream);
}